// Round 1
// baseline (839.970 us; speedup 1.0000x reference)
//
#include <hip/hip_runtime.h>
#include <math.h>

#define NSD 9
#define NPD 2
#define NAD 7
#define NH  256
#define NIN 16   // NSD + NAD

// ---------------------------------------------------------------------------
// Kernel 1: action proposal + candidate generation.
// One wave (64 lanes) per batch element; 4 waves per 256-thread block.
//   h = relu(x @ pw1 + pb1)   (lane holds h[lane + 64i], i=0..3)
//   base = tanh(h @ pw2 + pb2)  via 64-lane xor-butterfly reductions
//   cand[s,b,j] = clip(base[j] + 0.2*noise[s,b,j], -1, 1)  (lanes 0..55)
// ---------------------------------------------------------------------------
__global__ __launch_bounds__(256) void k_proposal(
    const float* __restrict__ state, const float* __restrict__ proprio,
    const float* __restrict__ noise, const float* __restrict__ pw1,
    const float* __restrict__ pb1, const float* __restrict__ pw2,
    const float* __restrict__ pb2, float* __restrict__ cand, int B)
{
    const int wave = threadIdx.x >> 6;
    const int lane = threadIdx.x & 63;
    const int b = blockIdx.x * 4 + wave;
    if (b >= B) return;

    float x[11];
#pragma unroll
    for (int k = 0; k < 9; ++k) x[k] = state[b * NSD + k];
    x[9]  = proprio[b * NPD + 0];
    x[10] = proprio[b * NPD + 1];

    float hc[4];
#pragma unroll
    for (int i = 0; i < 4; ++i) {
        const int c = lane + 64 * i;
        float acc = pb1[c];
#pragma unroll
        for (int k = 0; k < 11; ++k) acc = fmaf(x[k], pw1[k * NH + c], acc);
        hc[i] = fmaxf(acc, 0.0f);
    }

    float base[7];
#pragma unroll
    for (int j = 0; j < 7; ++j) {
        float p = 0.0f;
#pragma unroll
        for (int i = 0; i < 4; ++i)
            p = fmaf(hc[i], pw2[(lane + 64 * i) * NAD + j], p);
        // xor-butterfly: every lane ends with the full 256-sum
#pragma unroll
        for (int off = 32; off >= 1; off >>= 1) p += __shfl_xor(p, off, 64);
        base[j] = tanhf(p + pb2[j]);
    }

    if (lane < 8 * NAD) {
        const int s = lane / NAD, j = lane % NAD;
        float bj = base[0];
#pragma unroll
        for (int jj = 1; jj < 7; ++jj) if (j == jj) bj = base[jj];
        float v = bj + 0.2f * noise[((size_t)s * B + b) * NAD + j];
        v = fminf(fmaxf(v, -1.0f), 1.0f);
        cand[((size_t)s * B + b) * NAD + j] = v;
    }
}

// ---------------------------------------------------------------------------
// Kernel 2: horizon rollout + total cost. 16 (s,b) pairs per 256-thread block.
// Per step:
//   P1: h1 = relu(inp @ w1 + b1)   (16x16 @ 16x256)
//   P2: h2 = relu(h1 @ w2 + b2)    (16x256 @ 256x256)  -- dominant
//   P3: sim' = h2 @ w3 + b3; cost += ||sim'[:3]-tgt||^2
// Main matmuls: per-thread 4 rows x 4 cols register tile; A from LDS
// (row-major, stride 260 -> 16B aligned), W as float4 from global (L1/L2).
// ---------------------------------------------------------------------------
__global__ __launch_bounds__(256) void k_rollout(
    const float* __restrict__ state, const float* __restrict__ target,
    const float* __restrict__ cand,
    const float* __restrict__ w1, const float* __restrict__ b1,
    const float* __restrict__ w2, const float* __restrict__ b2,
    const float* __restrict__ w3, const float* __restrict__ b3,
    const int* __restrict__ hor_ptr, float* __restrict__ cost, int B)
{
    __shared__ float inpR[16][20];    // [pair][feature]; 0..8 sim, 9..15 cand (cand constant)
    __shared__ float h1R[16][260];    // stride 260: 16B-aligned float4 rows
    __shared__ float h2R[16][260];
    __shared__ float tgt[16][4];
    __shared__ float sq[16][4];
    __shared__ float costAcc[16];

    const int tid = threadIdx.x;
    const int p0 = blockIdx.x * 16;   // B % 16 == 0 -> block never straddles s
    const int s  = p0 / B;
    const int b0 = p0 % B;

    if (tid < 144) { int r = tid / 9, k = tid % 9;
        inpR[r][k] = state[(b0 + r) * NSD + k]; }
    if (tid < 112) { int r = tid / 7, j = tid % 7;
        inpR[r][NSD + j] = cand[((size_t)s * B + (b0 + r)) * NAD + j]; }
    if (tid < 48)  { int r = tid / 3, c = tid % 3;
        tgt[r][c] = target[(b0 + r) * 3 + c]; }
    if (tid < 16)  costAcc[tid] = 0.0f;
    __syncthreads();

    const int r0 = (tid >> 6) << 2;   // wave id * 4  (wave-uniform -> LDS broadcast)
    const int c0 = (tid & 63) << 2;   // 64 lanes cover all 256 cols
    const int horizon = *hor_ptr;

    const float4 b1v = *(const float4*)&b1[c0];
    const float4 b2v = *(const float4*)&b2[c0];

    for (int h = 0; h < horizon; ++h) {
        // ---- P1: h1 = relu(inp @ w1 + b1), K=16 ----
        {
            float acc[4][4];
#pragma unroll
            for (int i = 0; i < 4; ++i) {
                acc[i][0] = b1v.x; acc[i][1] = b1v.y;
                acc[i][2] = b1v.z; acc[i][3] = b1v.w;
            }
#pragma unroll
            for (int k = 0; k < NIN; ++k) {
                const float4 w = *(const float4*)&w1[k * NH + c0];
                float a[4];
#pragma unroll
                for (int i = 0; i < 4; ++i) a[i] = inpR[r0 + i][k];
#pragma unroll
                for (int i = 0; i < 4; ++i) {
                    acc[i][0] = fmaf(a[i], w.x, acc[i][0]);
                    acc[i][1] = fmaf(a[i], w.y, acc[i][1]);
                    acc[i][2] = fmaf(a[i], w.z, acc[i][2]);
                    acc[i][3] = fmaf(a[i], w.w, acc[i][3]);
                }
            }
#pragma unroll
            for (int i = 0; i < 4; ++i) {
                float4 v;
                v.x = fmaxf(acc[i][0], 0.0f); v.y = fmaxf(acc[i][1], 0.0f);
                v.z = fmaxf(acc[i][2], 0.0f); v.w = fmaxf(acc[i][3], 0.0f);
                *(float4*)&h1R[r0 + i][c0] = v;
            }
        }
        __syncthreads();

        // ---- P2: h2 = relu(h1 @ w2 + b2), K=256 (dominant) ----
        {
            float acc[4][4];
#pragma unroll
            for (int i = 0; i < 4; ++i) {
                acc[i][0] = b2v.x; acc[i][1] = b2v.y;
                acc[i][2] = b2v.z; acc[i][3] = b2v.w;
            }
#pragma unroll 4
            for (int k = 0; k < NH; ++k) {
                const float4 w = *(const float4*)&w2[k * NH + c0];
                float a[4];
#pragma unroll
                for (int i = 0; i < 4; ++i) a[i] = h1R[r0 + i][k];
#pragma unroll
                for (int i = 0; i < 4; ++i) {
                    acc[i][0] = fmaf(a[i], w.x, acc[i][0]);
                    acc[i][1] = fmaf(a[i], w.y, acc[i][1]);
                    acc[i][2] = fmaf(a[i], w.z, acc[i][2]);
                    acc[i][3] = fmaf(a[i], w.w, acc[i][3]);
                }
            }
#pragma unroll
            for (int i = 0; i < 4; ++i) {
                float4 v;
                v.x = fmaxf(acc[i][0], 0.0f); v.y = fmaxf(acc[i][1], 0.0f);
                v.z = fmaxf(acc[i][2], 0.0f); v.w = fmaxf(acc[i][3], 0.0f);
                *(float4*)&h2R[r0 + i][c0] = v;
            }
        }
        __syncthreads();

        // ---- P3: sim' = h2 @ w3 + b3; write back into inpR[.][0..8] ----
        if (tid < 144) {
            const int r = tid / 9, j = tid % 9;
            float a0 = 0.f, a1 = 0.f, a2 = 0.f, a3 = 0.f;
#pragma unroll 4
            for (int k = 0; k < NH; k += 4) {
                a0 = fmaf(h2R[r][k + 0], w3[(k + 0) * NSD + j], a0);
                a1 = fmaf(h2R[r][k + 1], w3[(k + 1) * NSD + j], a1);
                a2 = fmaf(h2R[r][k + 2], w3[(k + 2) * NSD + j], a2);
                a3 = fmaf(h2R[r][k + 3], w3[(k + 3) * NSD + j], a3);
            }
            const float acc = b3[j] + ((a0 + a1) + (a2 + a3));
            inpR[r][j] = acc;   // inpR reads finished two barriers ago
            if (j < 3) { const float d = acc - tgt[r][j]; sq[r][j] = d * d; }
        }
        __syncthreads();
        // deterministic cost accumulate (no atomics); safe to overlap next P1
        if (tid < 16) costAcc[tid] += sq[tid][0] + sq[tid][1] + sq[tid][2];
    }

    if (tid < 16) cost[(size_t)s * B + b0 + tid] = costAcc[tid];
}

// ---------------------------------------------------------------------------
// Kernel 3: first-argmin over samples + gather best action.
// ---------------------------------------------------------------------------
__global__ __launch_bounds__(256) void k_select(
    const float* __restrict__ cost, const float* __restrict__ cand,
    float* __restrict__ out, int B, int S)
{
    const int b = blockIdx.x * 256 + threadIdx.x;
    if (b >= B) return;
    float best = cost[b];
    int bs = 0;
    for (int s = 1; s < S; ++s) {
        const float c = cost[(size_t)s * B + b];
        if (c < best) { best = c; bs = s; }   // strict '<' == first argmin
    }
#pragma unroll
    for (int j = 0; j < NAD; ++j)
        out[b * NAD + j] = cand[((size_t)bs * B + b) * NAD + j];
}

// ---------------------------------------------------------------------------
extern "C" void kernel_launch(void* const* d_in, const int* in_sizes, int n_in,
                              void* d_out, int out_size, void* d_ws, size_t ws_size,
                              hipStream_t stream)
{
    const float* state   = (const float*)d_in[0];
    const float* proprio = (const float*)d_in[1];
    const float* target  = (const float*)d_in[2];
    const float* noise   = (const float*)d_in[3];
    const float* pw1     = (const float*)d_in[4];
    const float* pb1     = (const float*)d_in[5];
    const float* pw2     = (const float*)d_in[6];
    const float* pb2     = (const float*)d_in[7];
    const float* w1      = (const float*)d_in[8];
    const float* b1      = (const float*)d_in[9];
    const float* w2      = (const float*)d_in[10];
    const float* b2      = (const float*)d_in[11];
    const float* w3      = (const float*)d_in[12];
    const float* b3      = (const float*)d_in[13];
    const int*   horizon = (const int*)d_in[14];

    const int B = in_sizes[0] / NSD;             // 8192
    const int S = in_sizes[3] / (B * NAD);       // 8

    float* cand = (float*)d_ws;                  // S*B*7 floats
    float* cost = cand + (size_t)S * B * NAD;    // S*B floats
    float* out  = (float*)d_out;

    k_proposal<<<dim3((B + 3) / 4), dim3(256), 0, stream>>>(
        state, proprio, noise, pw1, pb1, pw2, pb2, cand, B);
    k_rollout<<<dim3((S * B) / 16), dim3(256), 0, stream>>>(
        state, target, cand, w1, b1, w2, b2, w3, b3, horizon, cost, B);
    k_select<<<dim3((B + 255) / 256), dim3(256), 0, stream>>>(
        cost, cand, out, B, S);
}

// Round 2
// 727.792 us; speedup vs baseline: 1.1541x; 1.1541x over previous
//
#include <hip/hip_runtime.h>
#include <math.h>

#define NSD 9
#define NPD 2
#define NAD 7
#define NH  256
#define NIN 16   // NSD + NAD

// ---------------------------------------------------------------------------
// Kernel 1: action proposal + candidate generation (unchanged from R1).
// ---------------------------------------------------------------------------
__global__ __launch_bounds__(256) void k_proposal(
    const float* __restrict__ state, const float* __restrict__ proprio,
    const float* __restrict__ noise, const float* __restrict__ pw1,
    const float* __restrict__ pb1, const float* __restrict__ pw2,
    const float* __restrict__ pb2, float* __restrict__ cand, int B)
{
    const int wave = threadIdx.x >> 6;
    const int lane = threadIdx.x & 63;
    const int b = blockIdx.x * 4 + wave;
    if (b >= B) return;

    float x[11];
#pragma unroll
    for (int k = 0; k < 9; ++k) x[k] = state[b * NSD + k];
    x[9]  = proprio[b * NPD + 0];
    x[10] = proprio[b * NPD + 1];

    float hc[4];
#pragma unroll
    for (int i = 0; i < 4; ++i) {
        const int c = lane + 64 * i;
        float acc = pb1[c];
#pragma unroll
        for (int k = 0; k < 11; ++k) acc = fmaf(x[k], pw1[k * NH + c], acc);
        hc[i] = fmaxf(acc, 0.0f);
    }

    float base[7];
#pragma unroll
    for (int j = 0; j < 7; ++j) {
        float p = 0.0f;
#pragma unroll
        for (int i = 0; i < 4; ++i)
            p = fmaf(hc[i], pw2[(lane + 64 * i) * NAD + j], p);
#pragma unroll
        for (int off = 32; off >= 1; off >>= 1) p += __shfl_xor(p, off, 64);
        base[j] = tanhf(p + pb2[j]);
    }

    if (lane < 8 * NAD) {
        const int s = lane / NAD, j = lane % NAD;
        float bj = base[0];
#pragma unroll
        for (int jj = 1; jj < 7; ++jj) if (j == jj) bj = base[jj];
        float v = bj + 0.2f * noise[((size_t)s * B + b) * NAD + j];
        v = fminf(fmaxf(v, -1.0f), 1.0f);
        cand[((size_t)s * B + b) * NAD + j] = v;
    }
}

// ---------------------------------------------------------------------------
// Kernel 2: horizon rollout. 512 threads, 64 (s,b) pairs per block.
// Each wave: 8 rows x 256 cols (acc[8][4] per lane). One block per CU
// (138.5 KB LDS) -> all 8 waves stream the same w2 rows in near-lockstep,
// so L1 filters the redundant streams; w2 reuse/row = 8 (was 4).
// h1/h2 rows unpadded: a-reads are wave-uniform b128 broadcasts, writes are
// intra-row float4 -> conflict-free.
// ---------------------------------------------------------------------------
__global__ __launch_bounds__(512) void k_rollout(
    const float* __restrict__ state, const float* __restrict__ target,
    const float* __restrict__ cand,
    const float* __restrict__ w1, const float* __restrict__ b1,
    const float* __restrict__ w2, const float* __restrict__ b2,
    const float* __restrict__ w3, const float* __restrict__ b3,
    const int* __restrict__ hor_ptr, float* __restrict__ cost, int B)
{
    __shared__ float inpR[64][20];   // [row][feature] 0..8 sim, 9..15 cand
    __shared__ float h1R[64][NH];
    __shared__ float h2R[64][NH];
    __shared__ float tgt[64][4];
    __shared__ float sq[64][4];
    __shared__ float costAcc[64];

    const int tid = threadIdx.x;
    const int p0 = blockIdx.x * 64;  // B % 64 == 0 -> block never straddles s
    const int s  = p0 / B;
    const int b0 = p0 % B;

    for (int idx = tid; idx < 64 * NSD; idx += 512) {
        const int r = idx / NSD, k = idx % NSD;
        inpR[r][k] = state[(b0 + r) * NSD + k];
    }
    if (tid < 64 * NAD) {
        const int r = tid / NAD, j = tid % NAD;
        inpR[r][NSD + j] = cand[((size_t)s * B + (b0 + r)) * NAD + j];
    }
    if (tid < 64 * 3) {
        const int r = tid / 3, c = tid % 3;
        tgt[r][c] = target[(b0 + r) * 3 + c];
    }
    if (tid < 64) costAcc[tid] = 0.0f;
    __syncthreads();

    const int r0 = (tid >> 6) * 8;   // wave id * 8 rows (wave-uniform)
    const int c0 = (tid & 63) * 4;   // 64 lanes x 4 = 256 cols
    const int horizon = *hor_ptr;

    const float4 b1v = *(const float4*)&b1[c0];
    const float4 b2v = *(const float4*)&b2[c0];

    for (int h = 0; h < horizon; ++h) {
        // ---- P1: h1 = relu(inp @ w1 + b1), K=16 ----
        {
            float acc[8][4];
#pragma unroll
            for (int i = 0; i < 8; ++i) {
                acc[i][0] = b1v.x; acc[i][1] = b1v.y;
                acc[i][2] = b1v.z; acc[i][3] = b1v.w;
            }
#pragma unroll
            for (int k = 0; k < NIN; k += 4) {
                float4 a[8];
#pragma unroll
                for (int i = 0; i < 8; ++i) a[i] = *(const float4*)&inpR[r0 + i][k];
                const float4 wv0 = *(const float4*)&w1[(k + 0) * NH + c0];
                const float4 wv1 = *(const float4*)&w1[(k + 1) * NH + c0];
                const float4 wv2 = *(const float4*)&w1[(k + 2) * NH + c0];
                const float4 wv3 = *(const float4*)&w1[(k + 3) * NH + c0];
#pragma unroll
                for (int i = 0; i < 8; ++i) {
                    acc[i][0] = fmaf(a[i].x, wv0.x, acc[i][0]);
                    acc[i][1] = fmaf(a[i].x, wv0.y, acc[i][1]);
                    acc[i][2] = fmaf(a[i].x, wv0.z, acc[i][2]);
                    acc[i][3] = fmaf(a[i].x, wv0.w, acc[i][3]);
                    acc[i][0] = fmaf(a[i].y, wv1.x, acc[i][0]);
                    acc[i][1] = fmaf(a[i].y, wv1.y, acc[i][1]);
                    acc[i][2] = fmaf(a[i].y, wv1.z, acc[i][2]);
                    acc[i][3] = fmaf(a[i].y, wv1.w, acc[i][3]);
                    acc[i][0] = fmaf(a[i].z, wv2.x, acc[i][0]);
                    acc[i][1] = fmaf(a[i].z, wv2.y, acc[i][1]);
                    acc[i][2] = fmaf(a[i].z, wv2.z, acc[i][2]);
                    acc[i][3] = fmaf(a[i].z, wv2.w, acc[i][3]);
                    acc[i][0] = fmaf(a[i].w, wv3.x, acc[i][0]);
                    acc[i][1] = fmaf(a[i].w, wv3.y, acc[i][1]);
                    acc[i][2] = fmaf(a[i].w, wv3.z, acc[i][2]);
                    acc[i][3] = fmaf(a[i].w, wv3.w, acc[i][3]);
                }
            }
#pragma unroll
            for (int i = 0; i < 8; ++i) {
                float4 v;
                v.x = fmaxf(acc[i][0], 0.0f); v.y = fmaxf(acc[i][1], 0.0f);
                v.z = fmaxf(acc[i][2], 0.0f); v.w = fmaxf(acc[i][3], 0.0f);
                *(float4*)&h1R[r0 + i][c0] = v;
            }
        }
        __syncthreads();

        // ---- P2: h2 = relu(h1 @ w2 + b2), K=256 (dominant) ----
        {
            float acc[8][4];
#pragma unroll
            for (int i = 0; i < 8; ++i) {
                acc[i][0] = b2v.x; acc[i][1] = b2v.y;
                acc[i][2] = b2v.z; acc[i][3] = b2v.w;
            }
#pragma unroll 2
            for (int k = 0; k < NH; k += 4) {
                float4 a[8];
#pragma unroll
                for (int i = 0; i < 8; ++i) a[i] = *(const float4*)&h1R[r0 + i][k];
                const float4 wv0 = *(const float4*)&w2[(k + 0) * NH + c0];
                const float4 wv1 = *(const float4*)&w2[(k + 1) * NH + c0];
                const float4 wv2 = *(const float4*)&w2[(k + 2) * NH + c0];
                const float4 wv3 = *(const float4*)&w2[(k + 3) * NH + c0];
#pragma unroll
                for (int i = 0; i < 8; ++i) {
                    acc[i][0] = fmaf(a[i].x, wv0.x, acc[i][0]);
                    acc[i][1] = fmaf(a[i].x, wv0.y, acc[i][1]);
                    acc[i][2] = fmaf(a[i].x, wv0.z, acc[i][2]);
                    acc[i][3] = fmaf(a[i].x, wv0.w, acc[i][3]);
                    acc[i][0] = fmaf(a[i].y, wv1.x, acc[i][0]);
                    acc[i][1] = fmaf(a[i].y, wv1.y, acc[i][1]);
                    acc[i][2] = fmaf(a[i].y, wv1.z, acc[i][2]);
                    acc[i][3] = fmaf(a[i].y, wv1.w, acc[i][3]);
                    acc[i][0] = fmaf(a[i].z, wv2.x, acc[i][0]);
                    acc[i][1] = fmaf(a[i].z, wv2.y, acc[i][1]);
                    acc[i][2] = fmaf(a[i].z, wv2.z, acc[i][2]);
                    acc[i][3] = fmaf(a[i].z, wv2.w, acc[i][3]);
                    acc[i][0] = fmaf(a[i].w, wv3.x, acc[i][0]);
                    acc[i][1] = fmaf(a[i].w, wv3.y, acc[i][1]);
                    acc[i][2] = fmaf(a[i].w, wv3.z, acc[i][2]);
                    acc[i][3] = fmaf(a[i].w, wv3.w, acc[i][3]);
                }
            }
#pragma unroll
            for (int i = 0; i < 8; ++i) {
                float4 v;
                v.x = fmaxf(acc[i][0], 0.0f); v.y = fmaxf(acc[i][1], 0.0f);
                v.z = fmaxf(acc[i][2], 0.0f); v.w = fmaxf(acc[i][3], 0.0f);
                *(float4*)&h2R[r0 + i][c0] = v;
            }
        }
        __syncthreads();

        // ---- P3: sim' = h2 @ w3 + b3; cost term ----
        for (int idx = tid; idx < 64 * NSD; idx += 512) {
            const int r = idx / NSD, j = idx - (idx / NSD) * NSD;
            float a0 = 0.f, a1 = 0.f, a2 = 0.f, a3 = 0.f;
#pragma unroll 4
            for (int k = 0; k < NH; k += 4) {
                const float4 hv = *(const float4*)&h2R[r][k];
                a0 = fmaf(hv.x, w3[(k + 0) * NSD + j], a0);
                a1 = fmaf(hv.y, w3[(k + 1) * NSD + j], a1);
                a2 = fmaf(hv.z, w3[(k + 2) * NSD + j], a2);
                a3 = fmaf(hv.w, w3[(k + 3) * NSD + j], a3);
            }
            const float accv = b3[j] + ((a0 + a1) + (a2 + a3));
            inpR[r][j] = accv;   // inpR reads finished two barriers ago
            if (j < 3) { const float d = accv - tgt[r][j]; sq[r][j] = d * d; }
        }
        __syncthreads();
        if (tid < 64) costAcc[tid] += sq[tid][0] + sq[tid][1] + sq[tid][2];
    }

    if (tid < 64) cost[(size_t)s * B + b0 + tid] = costAcc[tid];
}

// ---------------------------------------------------------------------------
// Kernel 3: first-argmin over samples + gather best action (unchanged).
// ---------------------------------------------------------------------------
__global__ __launch_bounds__(256) void k_select(
    const float* __restrict__ cost, const float* __restrict__ cand,
    float* __restrict__ out, int B, int S)
{
    const int b = blockIdx.x * 256 + threadIdx.x;
    if (b >= B) return;
    float best = cost[b];
    int bs = 0;
    for (int s = 1; s < S; ++s) {
        const float c = cost[(size_t)s * B + b];
        if (c < best) { best = c; bs = s; }
    }
#pragma unroll
    for (int j = 0; j < NAD; ++j)
        out[b * NAD + j] = cand[((size_t)bs * B + b) * NAD + j];
}

// ---------------------------------------------------------------------------
extern "C" void kernel_launch(void* const* d_in, const int* in_sizes, int n_in,
                              void* d_out, int out_size, void* d_ws, size_t ws_size,
                              hipStream_t stream)
{
    const float* state   = (const float*)d_in[0];
    const float* proprio = (const float*)d_in[1];
    const float* target  = (const float*)d_in[2];
    const float* noise   = (const float*)d_in[3];
    const float* pw1     = (const float*)d_in[4];
    const float* pb1     = (const float*)d_in[5];
    const float* pw2     = (const float*)d_in[6];
    const float* pb2     = (const float*)d_in[7];
    const float* w1      = (const float*)d_in[8];
    const float* b1      = (const float*)d_in[9];
    const float* w2      = (const float*)d_in[10];
    const float* b2      = (const float*)d_in[11];
    const float* w3      = (const float*)d_in[12];
    const float* b3      = (const float*)d_in[13];
    const int*   horizon = (const int*)d_in[14];

    const int B = in_sizes[0] / NSD;             // 8192
    const int S = in_sizes[3] / (B * NAD);       // 8

    float* cand = (float*)d_ws;                  // S*B*7 floats
    float* cost = cand + (size_t)S * B * NAD;    // S*B floats
    float* out  = (float*)d_out;

    k_proposal<<<dim3((B + 3) / 4), dim3(256), 0, stream>>>(
        state, proprio, noise, pw1, pb1, pw2, pb2, cand, B);
    k_rollout<<<dim3((S * B) / 64), dim3(512), 0, stream>>>(
        state, target, cand, w1, b1, w2, b2, w3, b3, horizon, cost, B);
    k_select<<<dim3((B + 255) / 256), dim3(256), 0, stream>>>(
        cost, cand, out, B, S);
}

// Round 3
// 455.892 us; speedup vs baseline: 1.8425x; 1.5964x over previous
//
#include <hip/hip_runtime.h>
#include <math.h>

#define NSD 9
#define NPD 2
#define NAD 7
#define NH  256
#define NIN 16   // NSD + NAD

typedef _Float16 half8 __attribute__((ext_vector_type(8)));
typedef _Float16 half4 __attribute__((ext_vector_type(4)));
typedef float    floatx4 __attribute__((ext_vector_type(4)));

#define H2S 260            // h2R fp32 row stride (260 % 32 banks = 4 -> spread, R1-verified)
#define FRAG_H 528         // fp16 units per A-frag slot (1056 B = 1024 data + 32 pad)
#define LOSCALE 2048.0f
#define LOINV   (1.0f / 2048.0f)

// ---------------------------------------------------------------------------
// Pack w2 (fp32 [256][256]) into MFMA B-fragment-major fp16 hi/lo arrays.
// frag (t = n-tile 0..15, kc = k-chunk 0..7): lane l holds
// B[k = kc*32 + (l>>4)*8 + j][n = t*16 + (l&15)], j = 0..7 (16 B contiguous).
// hi at (bid*2+0)*512, lo (scaled by 2^11) at (bid*2+1)*512.
// ---------------------------------------------------------------------------
__global__ __launch_bounds__(64) void k_pack(const float* __restrict__ w2,
                                             _Float16* __restrict__ w2p)
{
    const int bid  = blockIdx.x;          // t*8 + kc
    const int lane = threadIdx.x;
    const int t = bid >> 3, kc = bid & 7;
    const int ln = lane & 15, quad = lane >> 4;
    half8 hv, lv;
#pragma unroll
    for (int j = 0; j < 8; ++j) {
        const int k = kc * 32 + quad * 8 + j;
        const int n = t * 16 + ln;
        const float x = w2[k * NH + n];
        const _Float16 h = (_Float16)x;
        hv[j] = h;
        lv[j] = (_Float16)((x - (float)h) * LOSCALE);
    }
    *(half8*)&w2p[(size_t)(bid * 2 + 0) * 512 + lane * 8] = hv;
    *(half8*)&w2p[(size_t)(bid * 2 + 1) * 512 + lane * 8] = lv;
}

// ---------------------------------------------------------------------------
// Kernel 1: action proposal + candidate generation (unchanged, verified).
// ---------------------------------------------------------------------------
__global__ __launch_bounds__(256) void k_proposal(
    const float* __restrict__ state, const float* __restrict__ proprio,
    const float* __restrict__ noise, const float* __restrict__ pw1,
    const float* __restrict__ pb1, const float* __restrict__ pw2,
    const float* __restrict__ pb2, float* __restrict__ cand, int B)
{
    const int wave = threadIdx.x >> 6;
    const int lane = threadIdx.x & 63;
    const int b = blockIdx.x * 4 + wave;
    if (b >= B) return;

    float x[11];
#pragma unroll
    for (int k = 0; k < 9; ++k) x[k] = state[b * NSD + k];
    x[9]  = proprio[b * NPD + 0];
    x[10] = proprio[b * NPD + 1];

    float hc[4];
#pragma unroll
    for (int i = 0; i < 4; ++i) {
        const int c = lane + 64 * i;
        float acc = pb1[c];
#pragma unroll
        for (int k = 0; k < 11; ++k) acc = fmaf(x[k], pw1[k * NH + c], acc);
        hc[i] = fmaxf(acc, 0.0f);
    }

    float base[7];
#pragma unroll
    for (int j = 0; j < 7; ++j) {
        float p = 0.0f;
#pragma unroll
        for (int i = 0; i < 4; ++i)
            p = fmaf(hc[i], pw2[(lane + 64 * i) * NAD + j], p);
#pragma unroll
        for (int off = 32; off >= 1; off >>= 1) p += __shfl_xor(p, off, 64);
        base[j] = tanhf(p + pb2[j]);
    }

    if (lane < 8 * NAD) {
        const int s = lane / NAD, j = lane % NAD;
        float bj = base[0];
#pragma unroll
        for (int jj = 1; jj < 7; ++jj) if (j == jj) bj = base[jj];
        float v = bj + 0.2f * noise[((size_t)s * B + b) * NAD + j];
        v = fminf(fmaxf(v, -1.0f), 1.0f);
        cand[((size_t)s * B + b) * NAD + j] = v;
    }
}

// ---------------------------------------------------------------------------
// Kernel 2: rollout. 512 threads, 64 (s,b) pairs per block, 1 block/CU (LDS).
// P1: fp32 VALU (8 rows/wave), epilogue splits h1 -> fp16 hi/lo in A-frag-
//     packed LDS (frag stride 1056 B -> P2 reads are conflict-free b128).
// P2: split-fp16 MFMA 16x16x32: acc1 = Ahi*Bhi; acc2 = Ahi*Blo' + Alo'*Bhi;
//     res = acc1 + 2^-11*acc2 + b2, relu -> h2R fp32.
// P3: fp32 VALU (unchanged, h2R stride 260).
// ---------------------------------------------------------------------------
__global__ __launch_bounds__(512, 2) void k_rollout(
    const float* __restrict__ state, const float* __restrict__ target,
    const float* __restrict__ cand,
    const float* __restrict__ w1, const float* __restrict__ b1,
    const _Float16* __restrict__ w2p, const float* __restrict__ b2,
    const float* __restrict__ w3, const float* __restrict__ b3,
    const int* __restrict__ hor_ptr, float* __restrict__ cost, int B)
{
    __shared__ float    inpR[64][20];
    __shared__ _Float16 h1hi[32 * FRAG_H];   // 32 frags (4 m-tiles x 8 k-chunks)
    __shared__ _Float16 h1lo[32 * FRAG_H];
    __shared__ float    h2R[64][H2S];
    __shared__ float    tgt[64][4];
    __shared__ float    sq[64][4];
    __shared__ float    costAcc[64];

    const int tid = threadIdx.x;
    const int p0 = blockIdx.x * 64;
    const int s  = p0 / B;
    const int b0 = p0 % B;

    for (int idx = tid; idx < 64 * NSD; idx += 512) {
        const int r = idx / NSD, k = idx % NSD;
        inpR[r][k] = state[(b0 + r) * NSD + k];
    }
    if (tid < 64 * NAD) {
        const int r = tid / NAD, j = tid % NAD;
        inpR[r][NSD + j] = cand[((size_t)s * B + (b0 + r)) * NAD + j];
    }
    if (tid < 64 * 3) {
        const int r = tid / 3, c = tid % 3;
        tgt[r][c] = target[(b0 + r) * 3 + c];
    }
    if (tid < 64) costAcc[tid] = 0.0f;
    __syncthreads();

    const int lane = tid & 63;
    const int wv   = tid >> 6;
    const int r0 = wv * 8;            // P1: wave's 8 rows
    const int c0 = lane * 4;          // P1: lane's 4 cols
    const int ln   = lane & 15;       // P2 frag coords
    const int quad = lane >> 4;
    const int horizon = *hor_ptr;

    const float4 b1v = *(const float4*)&b1[c0];
    // P1 epilogue frag-packed destination pieces (value (r,c0..c0+3)):
    const int kcq   = lane >> 3;            // k-chunk of c0
    const int quadp = (lane >> 1) & 3;      // octet-of-32 of c0
    const int j0    = (lane & 1) * 4;       // j offset within octet
    const float bb0 = b2[wv * 32 + ln];
    const float bb1 = b2[wv * 32 + 16 + ln];

    for (int h = 0; h < horizon; ++h) {
        // ---- P1: h1 = relu(inp @ w1 + b1), fp32, then split to frags ----
        {
            float acc[8][4];
#pragma unroll
            for (int i = 0; i < 8; ++i) {
                acc[i][0] = b1v.x; acc[i][1] = b1v.y;
                acc[i][2] = b1v.z; acc[i][3] = b1v.w;
            }
#pragma unroll
            for (int k = 0; k < NIN; k += 4) {
                float4 a[8];
#pragma unroll
                for (int i = 0; i < 8; ++i) a[i] = *(const float4*)&inpR[r0 + i][k];
                const float4 wv0 = *(const float4*)&w1[(k + 0) * NH + c0];
                const float4 wv1 = *(const float4*)&w1[(k + 1) * NH + c0];
                const float4 wv2 = *(const float4*)&w1[(k + 2) * NH + c0];
                const float4 wv3 = *(const float4*)&w1[(k + 3) * NH + c0];
#pragma unroll
                for (int i = 0; i < 8; ++i) {
                    acc[i][0] = fmaf(a[i].x, wv0.x, acc[i][0]);
                    acc[i][1] = fmaf(a[i].x, wv0.y, acc[i][1]);
                    acc[i][2] = fmaf(a[i].x, wv0.z, acc[i][2]);
                    acc[i][3] = fmaf(a[i].x, wv0.w, acc[i][3]);
                    acc[i][0] = fmaf(a[i].y, wv1.x, acc[i][0]);
                    acc[i][1] = fmaf(a[i].y, wv1.y, acc[i][1]);
                    acc[i][2] = fmaf(a[i].y, wv1.z, acc[i][2]);
                    acc[i][3] = fmaf(a[i].y, wv1.w, acc[i][3]);
                    acc[i][0] = fmaf(a[i].z, wv2.x, acc[i][0]);
                    acc[i][1] = fmaf(a[i].z, wv2.y, acc[i][1]);
                    acc[i][2] = fmaf(a[i].z, wv2.z, acc[i][2]);
                    acc[i][3] = fmaf(a[i].z, wv2.w, acc[i][3]);
                    acc[i][0] = fmaf(a[i].w, wv3.x, acc[i][0]);
                    acc[i][1] = fmaf(a[i].w, wv3.y, acc[i][1]);
                    acc[i][2] = fmaf(a[i].w, wv3.z, acc[i][2]);
                    acc[i][3] = fmaf(a[i].w, wv3.w, acc[i][3]);
                }
            }
#pragma unroll
            for (int i = 0; i < 8; ++i) {
                const int r = r0 + i;
                const int fidx = ((r >> 4) * 8 + kcq) * FRAG_H
                               + (quadp * 16 + (r & 15)) * 8 + j0;
                half4 hv, lv;
#pragma unroll
                for (int q = 0; q < 4; ++q) {
                    const float v = fmaxf(acc[i][q], 0.0f);
                    const _Float16 hh = (_Float16)v;
                    hv[q] = hh;
                    lv[q] = (_Float16)((v - (float)hh) * LOSCALE);
                }
                *(half4*)&h1hi[fidx] = hv;
                *(half4*)&h1lo[fidx] = lv;
            }
        }
        __syncthreads();

        // ---- P2: h2 = relu(h1 @ w2 + b2) via split-fp16 MFMA ----
        {
            floatx4 acc1[4][2], acc2[4][2];
#pragma unroll
            for (int mt = 0; mt < 4; ++mt)
#pragma unroll
                for (int nt = 0; nt < 2; ++nt) {
                    acc1[mt][nt] = (floatx4){0.f, 0.f, 0.f, 0.f};
                    acc2[mt][nt] = (floatx4){0.f, 0.f, 0.f, 0.f};
                }
#pragma unroll 2
            for (int kc = 0; kc < 8; ++kc) {
                half8 hb[2], lb[2];
#pragma unroll
                for (int nt = 0; nt < 2; ++nt) {
                    const size_t fo =
                        (size_t)((((wv * 2 + nt) * 8 + kc) * 2)) * 512 + lane * 8;
                    hb[nt] = *(const half8*)&w2p[fo];
                    lb[nt] = *(const half8*)&w2p[fo + 512];
                }
                half8 ha[4], la[4];
#pragma unroll
                for (int mt = 0; mt < 4; ++mt) {
                    const int ao = (mt * 8 + kc) * FRAG_H + lane * 8;
                    ha[mt] = *(const half8*)&h1hi[ao];
                    la[mt] = *(const half8*)&h1lo[ao];
                }
#pragma unroll
                for (int mt = 0; mt < 4; ++mt)
#pragma unroll
                    for (int nt = 0; nt < 2; ++nt) {
                        acc1[mt][nt] = __builtin_amdgcn_mfma_f32_16x16x32_f16(
                            ha[mt], hb[nt], acc1[mt][nt], 0, 0, 0);
                        acc2[mt][nt] = __builtin_amdgcn_mfma_f32_16x16x32_f16(
                            ha[mt], lb[nt], acc2[mt][nt], 0, 0, 0);
                        acc2[mt][nt] = __builtin_amdgcn_mfma_f32_16x16x32_f16(
                            la[mt], hb[nt], acc2[mt][nt], 0, 0, 0);
                    }
            }
#pragma unroll
            for (int mt = 0; mt < 4; ++mt)
#pragma unroll
                for (int nt = 0; nt < 2; ++nt) {
                    const float bb = nt ? bb1 : bb0;
                    const int n = wv * 32 + nt * 16 + ln;
#pragma unroll
                    for (int r = 0; r < 4; ++r) {
                        const float v =
                            fmaf(acc2[mt][nt][r], LOINV, acc1[mt][nt][r]) + bb;
                        h2R[mt * 16 + quad * 4 + r][n] = fmaxf(v, 0.0f);
                    }
                }
        }
        __syncthreads();

        // ---- P3: sim' = h2 @ w3 + b3; cost term (fp32 VALU) ----
        for (int idx = tid; idx < 64 * NSD; idx += 512) {
            const int r = idx / NSD, j = idx - (idx / NSD) * NSD;
            float a0 = 0.f, a1 = 0.f, a2 = 0.f, a3 = 0.f;
#pragma unroll 4
            for (int k = 0; k < NH; k += 4) {
                const float4 hv2 = *(const float4*)&h2R[r][k];
                a0 = fmaf(hv2.x, w3[(k + 0) * NSD + j], a0);
                a1 = fmaf(hv2.y, w3[(k + 1) * NSD + j], a1);
                a2 = fmaf(hv2.z, w3[(k + 2) * NSD + j], a2);
                a3 = fmaf(hv2.w, w3[(k + 3) * NSD + j], a3);
            }
            const float accv = b3[j] + ((a0 + a1) + (a2 + a3));
            inpR[r][j] = accv;
            if (j < 3) { const float d = accv - tgt[r][j]; sq[r][j] = d * d; }
        }
        __syncthreads();
        if (tid < 64) costAcc[tid] += sq[tid][0] + sq[tid][1] + sq[tid][2];
    }

    if (tid < 64) cost[(size_t)s * B + b0 + tid] = costAcc[tid];
}

// ---------------------------------------------------------------------------
// Kernel 3: first-argmin over samples + gather best action (unchanged).
// ---------------------------------------------------------------------------
__global__ __launch_bounds__(256) void k_select(
    const float* __restrict__ cost, const float* __restrict__ cand,
    float* __restrict__ out, int B, int S)
{
    const int b = blockIdx.x * 256 + threadIdx.x;
    if (b >= B) return;
    float best = cost[b];
    int bs = 0;
    for (int s = 1; s < S; ++s) {
        const float c = cost[(size_t)s * B + b];
        if (c < best) { best = c; bs = s; }
    }
#pragma unroll
    for (int j = 0; j < NAD; ++j)
        out[b * NAD + j] = cand[((size_t)bs * B + b) * NAD + j];
}

// ---------------------------------------------------------------------------
extern "C" void kernel_launch(void* const* d_in, const int* in_sizes, int n_in,
                              void* d_out, int out_size, void* d_ws, size_t ws_size,
                              hipStream_t stream)
{
    const float* state   = (const float*)d_in[0];
    const float* proprio = (const float*)d_in[1];
    const float* target  = (const float*)d_in[2];
    const float* noise   = (const float*)d_in[3];
    const float* pw1     = (const float*)d_in[4];
    const float* pb1     = (const float*)d_in[5];
    const float* pw2     = (const float*)d_in[6];
    const float* pb2     = (const float*)d_in[7];
    const float* w1      = (const float*)d_in[8];
    const float* b1      = (const float*)d_in[9];
    const float* w2      = (const float*)d_in[10];
    const float* b2      = (const float*)d_in[11];
    const float* w3      = (const float*)d_in[12];
    const float* b3      = (const float*)d_in[13];
    const int*   horizon = (const int*)d_in[14];

    const int B = in_sizes[0] / NSD;             // 8192
    const int S = in_sizes[3] / (B * NAD);       // 8

    float* cand = (float*)d_ws;                           // S*B*7 floats
    float* cost = cand + (size_t)S * B * NAD;             // S*B floats
    _Float16* w2p = (_Float16*)(cost + (size_t)S * B);    // 128 KB hi + 128 KB lo
    float* out  = (float*)d_out;

    k_pack<<<dim3(128), dim3(64), 0, stream>>>(w2, w2p);
    k_proposal<<<dim3((B + 3) / 4), dim3(256), 0, stream>>>(
        state, proprio, noise, pw1, pb1, pw2, pb2, cand, B);
    k_rollout<<<dim3((S * B) / 64), dim3(512), 0, stream>>>(
        state, target, cand, w1, b1, w2p, b2, w3, b3, horizon, cost, B);
    k_select<<<dim3((B + 255) / 256), dim3(256), 0, stream>>>(
        cost, cand, out, B, S);
}